// Round 9
// baseline (70.781 us; speedup 1.0000x reference)
//
#include <hip/hip_runtime.h>

#define KS 10
#define NT 256
#define W  512   // level-0 samples per WAVE (each wave fully independent)

// Per-wave LDS arena (floats): only a1..a3 live in LDS.
//  sa1 [312] : a1 slots, pad 28 | own 256 | pad 28
//  sa2 [152] : a2 slots, pad 12 | own 128 | pad 12
//  sa3 [72]  : a3 slots, pad 4  | own 64  | pad 4
#define ARENA (312 + 152 + 72)   // 536 floats = 2144 B per wave

#define FENCE() asm volatile("s_waitcnt lgkmcnt(0)" ::: "memory")

typedef float f4 __attribute__((ext_vector_type(4)));   // native vector for nontemporal builtin

struct OutPtrs { float* a[4]; float* d[4]; };

// levels 2..4: EXT extended outputs from LDS (float2 -> ds_read_b64), own a/d to global (nt)
template<int EXT, int PADO, int OWN, bool TO_LDS>
__device__ __forceinline__ void wave_level(const float* __restrict__ sIn,
                                           float* __restrict__ sOut,
                                           const float* h,
                                           float* __restrict__ aRow,
                                           float* __restrict__ dRow,
                                           int obase, int lane)
{
    constexpr int ITERS = (EXT + 63) / 64;
#pragma unroll
    for (int i = 0; i < ITERS; ++i) {
        const int t = lane + 64 * i;
        if ((EXT % 64 == 0) || (t < EXT)) {
            const float2* p2 = reinterpret_cast<const float2*>(sIn);
            float xin[10];
#pragma unroll
            for (int j = 0; j < 5; ++j) {           // [2t, 2t+10) as 5x ds_read_b64
                const float2 v = p2[t + j];
                xin[2 * j] = v.x; xin[2 * j + 1] = v.y;
            }
            float aa = 0.0f, dd = 0.0f;
#pragma unroll
            for (int k = 0; k < KS; ++k) {
                aa = fmaf(xin[k], h[k], aa);
                dd = fmaf(xin[k], (k & 1) ? -h[KS - 1 - k] : h[KS - 1 - k], dd);
            }
            if (TO_LDS) sOut[t] = aa;
            const int rel = t - PADO;
            if (rel >= 0 && rel < OWN) {
                __builtin_nontemporal_store(aa, aRow + obase + rel);
                __builtin_nontemporal_store(dd, dRow + obase + rel);
            }
        }
    }
}

__device__ __forceinline__ void patchL(float* s, int P, int lane) {
    if (lane < P) s[lane] = 2.0f * s[P] - s[2 * P - lane];
}
__device__ __forceinline__ void patchR(float* s, int P, int E, int lane) {
    if (lane < P) { const int t = E + 1 + lane; s[t] = 2.0f * s[E] - s[2 * E - t]; }
}

__global__ __launch_bounds__(NT) void dwt_wave_kernel(
    const float* __restrict__ x, const float* __restrict__ hptr, OutPtrs op, int L0)
{
    const int tid  = threadIdx.x;
    const int lane = tid & 63;
    const int wv   = tid >> 6;

    // ---- bijective XCD swizzle (T1): nwg = 16384 = 8 * 2048.
    // Round-robin dispatch sends orig%8 -> XCD; give each XCD 2048 contiguous
    // wgids = 64 complete rows, so a row's 32 blocks (halo partners) share one L2.
    const int nwg  = gridDim.x;                 // 16384
    const int cpx  = nwg >> 3;                  // 2048
    const int orig = blockIdx.x;
    const int wg   = (orig & 7) * cpx + (orig >> 3);
    const int row  = wg >> 5;                   // 512 rows
    const int bx   = wg & 31;                   // 32 chunk-groups per row

    const int nc   = L0 / W;                    // 128 chunks per row
    const int c    = bx * (NT / 64) + wv;
    const bool left  = (c == 0);
    const bool right = (c == nc - 1);

    __shared__ __align__(16) float arena[(NT / 64) * ARENA];
    float* sa1 = arena + wv * ARENA;   // 312
    float* sa2 = sa1 + 312;            // 152
    float* sa3 = sa2 + 152;            // 72

    float h[KS];
#pragma unroll
    for (int k = 0; k < KS; ++k) h[k] = hptr[k];

    const int L1 = L0 >> 1, L2 = L0 >> 2, L3 = L0 >> 3, L4 = L0 >> 4;
    float* a0row = op.a[0] + (size_t)row * L1;  float* d0row = op.d[0] + (size_t)row * L1;
    float* a1row = op.a[1] + (size_t)row * L2;  float* d1row = op.d[1] + (size_t)row * L2;
    float* a2row = op.a[2] + (size_t)row * L3;  float* d2row = op.d[2] + (size_t)row * L3;
    float* a3row = op.a[3] + (size_t)row * L4;  float* d3row = op.d[3] + (size_t)row * L4;

    const float* xr = x + (size_t)row * (size_t)L0;
    const int o1 = c * 256;

    // ---- pad-slot x loads issued FIRST so their latency overlaps level-1 compute ----
    int ps = -1;
    float px[KS];
    {
        int v1p = 0;
        if (lane < 28)                     { ps = lane;              v1p = o1 - 28 + lane; }
        else if (lane >= 32 && lane < 60)  { ps = 284 + (lane - 32); v1p = o1 + 256 + (lane - 32); }
        const bool skip = (left && lane < 32) || (right && lane >= 32);
        if (skip) ps = -1;
        if (ps >= 0) {
            const int xb = 2 * v1p - 4;     // in-range for interior waves
#pragma unroll
            for (int k = 0; k < KS; ++k) px[k] = xr[xb + k];
        }
    }

    // ---- level 1: register-direct from global (no LDS on the x path) ----
    // thread owns a1/d1 at [o1+4*lane, o1+4*lane+4); needs x[X, X+16), X = 2*o1+8*lane-4
    {
        const int X = 2 * o1 + 8 * lane - 4;            // 16B-aligned
        float xv[16];
        const bool eT = (left && lane == 0) || (right && lane == 63);
        if (!eT) {
            const float4* p = reinterpret_cast<const float4*>(xr + X);
#pragma unroll
            for (int q = 0; q < 4; ++q) {
                const float4 v = p[q];
                xv[4 * q] = v.x; xv[4 * q + 1] = v.y; xv[4 * q + 2] = v.z; xv[4 * q + 3] = v.w;
            }
        } else {
#pragma unroll
            for (int t = 0; t < 16; ++t) {
                const int m = X + t;
                float v;
                if (m < 0)        v = 2.0f * xr[0]      - xr[-m];
                else if (m >= L0) v = 2.0f * xr[L0 - 1] - xr[2 * L0 - 2 - m];
                else              v = xr[m];
                xv[t] = v;
            }
        }
        float av[4], dv[4];
#pragma unroll
        for (int j = 0; j < 4; ++j) {
            float aa = 0.0f, dd = 0.0f;
#pragma unroll
            for (int k = 0; k < KS; ++k) {
                const float xx = xv[2 * j + k];
                aa = fmaf(xx, h[k], aa);
                dd = fmaf(xx, (k & 1) ? -h[KS - 1 - k] : h[KS - 1 - k], dd);
            }
            av[j] = aa; dv[j] = dd;
        }
        const int lane4 = 4 * lane;
        f4 avv = {av[0], av[1], av[2], av[3]};
        f4 dvv = {dv[0], dv[1], dv[2], dv[3]};
        __builtin_nontemporal_store(avv, reinterpret_cast<f4*>(a0row + o1 + lane4));
        __builtin_nontemporal_store(dvv, reinterpret_cast<f4*>(d0row + o1 + lane4));
        *reinterpret_cast<f4*>(sa1 + 28 + lane4) = avv;
    }

    // ---- finish a1 pad slots from the preloaded px ----
    if (ps >= 0) {
        float acc = 0.0f;
#pragma unroll
        for (int k = 0; k < KS; ++k) acc = fmaf(px[k], h[k], acc);
        sa1[ps] = acc;
    }
    FENCE();
    if (left)  { patchL(sa1, 28, lane);       FENCE(); }
    if (right) { patchR(sa1, 28, 283, lane);  FENCE(); }

    // ---- cascade levels 2..4 from LDS ----
    wave_level<152, 12, 128, true >(sa1, sa2, h, a1row, d1row, c * 128, lane);
    FENCE();
    if (left)  { patchL(sa2, 12, lane);       FENCE(); }
    if (right) { patchR(sa2, 12, 139, lane);  FENCE(); }

    wave_level< 72,  4,  64, true >(sa2, sa3, h, a2row, d2row, c * 64, lane);
    FENCE();
    if (left)  { patchL(sa3, 4, lane);        FENCE(); }
    if (right) { patchR(sa3, 4, 67, lane);    FENCE(); }

    wave_level< 32,  0,  32, false>(sa3, nullptr, h, a3row, d3row, c * 32, lane);
}

extern "C" void kernel_launch(void* const* d_in, const int* in_sizes, int n_in,
                              void* d_out, int out_size, void* d_ws, size_t ws_size,
                              hipStream_t stream) {
    (void)n_in; (void)d_ws; (void)ws_size; (void)out_size;

    const float* signal = (const float*)d_in[0];
    const float* h      = (const float*)d_in[1];
    float* out = (float*)d_out;

    const int L0 = 65536;
    const int R  = in_sizes[0] / L0;   // 512 rows
    const int LEVELS = 4;

    size_t s_off[4], d_off[4];
    {
        size_t off = 0;
        int L = L0;
        for (int l = 0; l < LEVELS; ++l) { s_off[l] = off; off += (size_t)R * (size_t)(L >> 1); L >>= 1; }
        L = L0;
        for (int l = 0; l < LEVELS; ++l) { d_off[l] = off; off += (size_t)R * (size_t)(L >> 1); L >>= 1; }
    }

    OutPtrs op;
    for (int l = 0; l < LEVELS; ++l) { op.a[l] = out + s_off[l]; op.d[l] = out + d_off[l]; }

    const int nwg = (L0 / W / (NT / 64)) * R;   // 32 * 512 = 16384 (divisible by 8)
    dwt_wave_kernel<<<dim3(nwg), dim3(NT), 0, stream>>>(signal, h, op, L0);
}

// Round 10
// 68.189 us; speedup vs baseline: 1.0380x; 1.0380x over previous
//
#include <hip/hip_runtime.h>

#define KS 10
#define NT 256
#define W  512   // level-0 samples per WAVE (each wave fully independent)

// Per-wave LDS arena (floats): only a1..a3 live in LDS.
//  sa1 [312] : a1 slots, pad 28 | own 256 | pad 28
//  sa2 [152] : a2 slots, pad 12 | own 128 | pad 12
//  sa3 [72]  : a3 slots, pad 4  | own 64  | pad 4
#define ARENA (312 + 152 + 72)   // 536 floats = 2144 B per wave

#define FENCE() asm volatile("s_waitcnt lgkmcnt(0)" ::: "memory")

typedef float f4 __attribute__((ext_vector_type(4)));   // native vector for nontemporal builtin

struct OutPtrs { float* a[4]; float* d[4]; };

// levels 2..4: EXT extended outputs from LDS (float2 -> ds_read_b64), own a/d to global (nt)
template<int EXT, int PADO, int OWN, bool TO_LDS>
__device__ __forceinline__ void wave_level(const float* __restrict__ sIn,
                                           float* __restrict__ sOut,
                                           const float* h,
                                           float* __restrict__ aRow,
                                           float* __restrict__ dRow,
                                           int obase, int lane)
{
    constexpr int ITERS = (EXT + 63) / 64;
#pragma unroll
    for (int i = 0; i < ITERS; ++i) {
        const int t = lane + 64 * i;
        if ((EXT % 64 == 0) || (t < EXT)) {
            const float2* p2 = reinterpret_cast<const float2*>(sIn);
            float xin[10];
#pragma unroll
            for (int j = 0; j < 5; ++j) {           // [2t, 2t+10) as 5x ds_read_b64
                const float2 v = p2[t + j];
                xin[2 * j] = v.x; xin[2 * j + 1] = v.y;
            }
            float aa = 0.0f, dd = 0.0f;
#pragma unroll
            for (int k = 0; k < KS; ++k) {
                aa = fmaf(xin[k], h[k], aa);
                dd = fmaf(xin[k], (k & 1) ? -h[KS - 1 - k] : h[KS - 1 - k], dd);
            }
            if (TO_LDS) sOut[t] = aa;
            const int rel = t - PADO;
            if (rel >= 0 && rel < OWN) {
                __builtin_nontemporal_store(aa, aRow + obase + rel);
                __builtin_nontemporal_store(dd, dRow + obase + rel);
            }
        }
    }
}

__device__ __forceinline__ void patchL(float* s, int P, int lane) {
    if (lane < P) s[lane] = 2.0f * s[P] - s[2 * P - lane];
}
__device__ __forceinline__ void patchR(float* s, int P, int E, int lane) {
    if (lane < P) { const int t = E + 1 + lane; s[t] = 2.0f * s[E] - s[2 * E - t]; }
}

__global__ __launch_bounds__(NT) void dwt_wave_kernel(
    const float* __restrict__ x, const float* __restrict__ hptr, OutPtrs op, int L0)
{
    const int tid  = threadIdx.x;
    const int lane = tid & 63;
    const int wv   = tid >> 6;
    const int row  = blockIdx.y;
    const int nc   = L0 / W;                    // 128 chunks per row
    const int c    = blockIdx.x * (NT / 64) + wv;
    const bool left  = (c == 0);
    const bool right = (c == nc - 1);

    __shared__ __align__(16) float arena[(NT / 64) * ARENA];
    float* sa1 = arena + wv * ARENA;   // 312
    float* sa2 = sa1 + 312;            // 152
    float* sa3 = sa2 + 152;            // 72

    float h[KS];
#pragma unroll
    for (int k = 0; k < KS; ++k) h[k] = hptr[k];

    const int L1 = L0 >> 1, L2 = L0 >> 2, L3 = L0 >> 3, L4 = L0 >> 4;
    float* a0row = op.a[0] + (size_t)row * L1;  float* d0row = op.d[0] + (size_t)row * L1;
    float* a1row = op.a[1] + (size_t)row * L2;  float* d1row = op.d[1] + (size_t)row * L2;
    float* a2row = op.a[2] + (size_t)row * L3;  float* d2row = op.d[2] + (size_t)row * L3;
    float* a3row = op.a[3] + (size_t)row * L4;  float* d3row = op.d[3] + (size_t)row * L4;

    const float* xr = x + (size_t)row * (size_t)L0;
    const int o1 = c * 256;

    // ---- pad-slot x loads issued FIRST so their latency overlaps level-1 compute ----
    int ps = -1;
    float px[KS];
    {
        int v1p = 0;
        if (lane < 28)                     { ps = lane;              v1p = o1 - 28 + lane; }
        else if (lane >= 32 && lane < 60)  { ps = 284 + (lane - 32); v1p = o1 + 256 + (lane - 32); }
        const bool skip = (left && lane < 32) || (right && lane >= 32);
        if (skip) ps = -1;
        if (ps >= 0) {
            const int xb = 2 * v1p - 4;     // in-range for interior waves
#pragma unroll
            for (int k = 0; k < KS; ++k) px[k] = xr[xb + k];
        }
    }

    // ---- level 1: register-direct from global (no LDS on the x path) ----
    // thread owns a1/d1 at [o1+4*lane, o1+4*lane+4); needs x[X, X+16), X = 2*o1+8*lane-4
    {
        const int X = 2 * o1 + 8 * lane - 4;            // 16B-aligned
        float xv[16];
        const bool eT = (left && lane == 0) || (right && lane == 63);
        if (!eT) {
            const float4* p = reinterpret_cast<const float4*>(xr + X);
#pragma unroll
            for (int q = 0; q < 4; ++q) {
                const float4 v = p[q];
                xv[4 * q] = v.x; xv[4 * q + 1] = v.y; xv[4 * q + 2] = v.z; xv[4 * q + 3] = v.w;
            }
        } else {
#pragma unroll
            for (int t = 0; t < 16; ++t) {
                const int m = X + t;
                float v;
                if (m < 0)        v = 2.0f * xr[0]      - xr[-m];
                else if (m >= L0) v = 2.0f * xr[L0 - 1] - xr[2 * L0 - 2 - m];
                else              v = xr[m];
                xv[t] = v;
            }
        }
        float av[4], dv[4];
#pragma unroll
        for (int j = 0; j < 4; ++j) {
            float aa = 0.0f, dd = 0.0f;
#pragma unroll
            for (int k = 0; k < KS; ++k) {
                const float xx = xv[2 * j + k];
                aa = fmaf(xx, h[k], aa);
                dd = fmaf(xx, (k & 1) ? -h[KS - 1 - k] : h[KS - 1 - k], dd);
            }
            av[j] = aa; dv[j] = dd;
        }
        const int lane4 = 4 * lane;
        f4 avv = {av[0], av[1], av[2], av[3]};
        f4 dvv = {dv[0], dv[1], dv[2], dv[3]};
        __builtin_nontemporal_store(avv, reinterpret_cast<f4*>(a0row + o1 + lane4));
        __builtin_nontemporal_store(dvv, reinterpret_cast<f4*>(d0row + o1 + lane4));
        *reinterpret_cast<f4*>(sa1 + 28 + lane4) = avv;
    }

    // ---- finish a1 pad slots from the preloaded px ----
    if (ps >= 0) {
        float acc = 0.0f;
#pragma unroll
        for (int k = 0; k < KS; ++k) acc = fmaf(px[k], h[k], acc);
        sa1[ps] = acc;
    }
    FENCE();
    if (left)  { patchL(sa1, 28, lane);       FENCE(); }
    if (right) { patchR(sa1, 28, 283, lane);  FENCE(); }

    // ---- cascade levels 2..4 from LDS ----
    wave_level<152, 12, 128, true >(sa1, sa2, h, a1row, d1row, c * 128, lane);
    FENCE();
    if (left)  { patchL(sa2, 12, lane);       FENCE(); }
    if (right) { patchR(sa2, 12, 139, lane);  FENCE(); }

    wave_level< 72,  4,  64, true >(sa2, sa3, h, a2row, d2row, c * 64, lane);
    FENCE();
    if (left)  { patchL(sa3, 4, lane);        FENCE(); }
    if (right) { patchR(sa3, 4, 67, lane);    FENCE(); }

    wave_level< 32,  0,  32, false>(sa3, nullptr, h, a3row, d3row, c * 32, lane);
}

extern "C" void kernel_launch(void* const* d_in, const int* in_sizes, int n_in,
                              void* d_out, int out_size, void* d_ws, size_t ws_size,
                              hipStream_t stream) {
    (void)n_in; (void)d_ws; (void)ws_size; (void)out_size;

    const float* signal = (const float*)d_in[0];
    const float* h      = (const float*)d_in[1];
    float* out = (float*)d_out;

    const int L0 = 65536;
    const int R  = in_sizes[0] / L0;   // 512 rows
    const int LEVELS = 4;

    size_t s_off[4], d_off[4];
    {
        size_t off = 0;
        int L = L0;
        for (int l = 0; l < LEVELS; ++l) { s_off[l] = off; off += (size_t)R * (size_t)(L >> 1); L >>= 1; }
        L = L0;
        for (int l = 0; l < LEVELS; ++l) { d_off[l] = off; off += (size_t)R * (size_t)(L >> 1); L >>= 1; }
    }

    OutPtrs op;
    for (int l = 0; l < LEVELS; ++l) { op.a[l] = out + s_off[l]; op.d[l] = out + d_off[l]; }

    dim3 grid(L0 / W / (NT / 64), R);   // 32 x 512 blocks, 4 independent waves each
    dim3 block(NT);
    dwt_wave_kernel<<<grid, block, 0, stream>>>(signal, h, op, L0);
}